// Round 15
// baseline (324.875 us; speedup 1.0000x reference)
//
#include <hip/hip_runtime.h>
#include <stdint.h>
#include <math.h>

typedef __bf16 bf16_t;
typedef float f32x4 __attribute__((ext_vector_type(4)));
typedef __bf16 bf16x8 __attribute__((ext_vector_type(8)));
typedef __bf16 bf16x4 __attribute__((ext_vector_type(4)));

#define D_ 1024
#define M_ 8192

__device__ __forceinline__ f32x4 mfma16(bf16x8 a, bf16x8 b, f32x4 c) {
  return __builtin_amdgcn_mfma_f32_16x16x32_bf16(a, b, c, 0, 0, 0);
}

__device__ __forceinline__ void gl_lds16(const bf16_t* g, bf16_t* l) {
  __builtin_amdgcn_global_load_lds(
      (const __attribute__((address_space(1))) unsigned int*)g,
      (__attribute__((address_space(3))) unsigned int*)l, 16, 0, 0);
}

// ---------------- all fp32 -> bf16 converts in ONE launch ----------------
__global__ __launch_bounds__(256) void cvt_all(
    const float* __restrict__ x,
    const float* __restrict__ w0, const float* __restrict__ w1,
    const float* __restrict__ w2, const float* __restrict__ w3,
    bf16_t* __restrict__ xb,
    bf16_t* __restrict__ d0, bf16_t* __restrict__ d1,
    bf16_t* __restrict__ d2, bf16_t* __restrict__ d3) {
  int b = blockIdx.x;
  const float* s;
  bf16_t* d;
  int i;
  if (b < 4096) {
    s = x; d = xb; i = b * 256 + threadIdx.x;
  } else {
    int g = b - 4096;
    int which = g >> 9;
    s = which == 0 ? w0 : which == 1 ? w1 : which == 2 ? w2 : w3;
    d = which == 0 ? d0 : which == 1 ? d1 : which == 2 ? d2 : d3;
    i = (g & 511) * 256 + threadIdx.x;
  }
  const f32x4* p = (const f32x4*)(s + (size_t)i * 8);
  f32x4 a = p[0], bb = p[1];
  bf16x8 o;
  o[0] = (bf16_t)a.x; o[1] = (bf16_t)a.y; o[2] = (bf16_t)a.z; o[3] = (bf16_t)a.w;
  o[4] = (bf16_t)bb.x; o[5] = (bf16_t)bb.y; o[6] = (bf16_t)bb.z; o[7] = (bf16_t)bb.w;
  *(bf16x8*)(d + (size_t)i * 8) = o;
}

#define LDSB(e) (*(const bf16x8*)(Sm + (e)))

// ============ 2-phase 128x256xBK32 core — 48 KiB LDS, 2 blocks/CU ==========
// Co-residency restored (m97 mechanism): second resident block hides the
// vmcnt(0)+barrier drain. Swizzle for 64B rows (4 slots of 16B):
// phys_slot = slot ^ ((row>>1)&3) -> 2-way bank alias = free; staging source
// col uses the same involution (linear DMA dest, rule #21).
#define STG32(b, kt)                                                          \
  {                                                                           \
    gl_lds16(Ap + (size_t)(m0 + (tid >> 2)) * 1024 + (kt) * 32 + scol,        \
             Sm + (b) * 12288 + tid * 8);                                     \
    _Pragma("unroll") for (int j = 0; j < 2; ++j)                             \
        gl_lds16(Bp + (size_t)(n0 + j * 128 + (tid >> 2)) * 1024 +            \
                     (kt) * 32 + scol,                                        \
                 Sm + (b) * 12288 + 4096 + j * 4096 + tid * 8);               \
  }

__device__ __forceinline__ void core_bk32(const bf16_t* __restrict__ Ap,
                                          const bf16_t* __restrict__ Bp,
                                          int m0, int n0, bf16_t* Sm,
                                          f32x4 acc[4][4]) {
  const int tid = threadIdx.x;
  const int l = tid & 63, w = tid >> 6;
  const int wm = w >> 2, wn = w & 3;
  const int lr = l & 15, lg = l >> 4;
  // staging source pre-swizzle: thread t -> row t>>2, phys slot t&3 must
  // hold logical slot (t&3)^((row>>1)&3) = (t&3)^((t>>3)&3)
  const int scol = ((tid & 3) ^ ((tid >> 3) & 3)) * 8;
  // read: row r, logical slot lg -> phys slot lg^((r>>1)&3); r>>1 dep = lr>>1
  const int sw = (lg ^ ((lr >> 1) & 3)) * 8;
  const int rdA = (wm * 64 + lr) * 32 + sw;
  const int rdB = 4096 + (wn * 64 + lr) * 32 + sw;

  STG32(0, 0)
  asm volatile("s_waitcnt vmcnt(0)" ::: "memory");
  __builtin_amdgcn_sched_barrier(0);
  __builtin_amdgcn_s_barrier();

  int cur = 0;
  for (int kt = 0; kt < 32; ++kt) {
    if (kt < 31) STG32(cur ^ 1, kt + 1)
    const int bb = cur * 12288;
    bf16x8 bfr[4];
#pragma unroll
    for (int fn = 0; fn < 4; ++fn) bfr[fn] = LDSB(bb + rdB + fn * 512);
#pragma unroll
    for (int fm = 0; fm < 4; ++fm) {
      bf16x8 a0 = LDSB(bb + rdA + fm * 512);
#pragma unroll
      for (int fn = 0; fn < 4; ++fn)
        acc[fm][fn] = mfma16(a0, bfr[fn], acc[fm][fn]);
    }
    asm volatile("s_waitcnt vmcnt(0)" ::: "memory");
    __builtin_amdgcn_sched_barrier(0);
    __builtin_amdgcn_s_barrier();
    cur ^= 1;
  }
}

// ---------------- QKV: 768 blocks, 2 blocks/CU ----------------
__global__ __launch_bounds__(512, 4) void gemm_qkv2(
    const bf16_t* __restrict__ A,
    const bf16_t* __restrict__ Wq, const bf16_t* __restrict__ Wk,
    const bf16_t* __restrict__ Wv,
    const float* __restrict__ bq, const float* __restrict__ bk,
    const float* __restrict__ bv,
    bf16_t* __restrict__ Oq, bf16_t* __restrict__ Ok, bf16_t* __restrict__ Ov) {
  __shared__ bf16_t Sm[24576];  // 48 KiB

  int wg = blockIdx.x;
  int xcd = wg & 7, local = wg >> 3;          // local 0..95
  int bm = xcd * 8 + (local & 7);             // 0..63
  int bnid = local >> 3;                      // 0..11
  int which = bnid >> 2;
  const bf16_t* Wsel = which == 0 ? Wq : (which == 1 ? Wk : Wv);
  const float* bias = which == 0 ? bq : (which == 1 ? bk : bv);
  bf16_t* O = which == 0 ? Oq : (which == 1 ? Ok : Ov);
  const float scale = which == 0 ? 0.18033688f : 1.0f;  // 0.125*log2(e) on Q
  const int m0 = bm * 128, n0 = (bnid & 3) * 256;

  f32x4 acc[4][4] = {};
  core_bk32(A, Wsel, m0, n0, Sm, acc);

  const int tid = threadIdx.x;
  const int l = tid & 63, w = tid >> 6;
  const int wm = w >> 2, wn = w & 3;
  const int lr = l & 15, lg = l >> 4;
#pragma unroll
  for (int fn = 0; fn < 4; ++fn) {
    int col = n0 + wn * 64 + fn * 16 + lr;
    float bb2 = bias[col];
#pragma unroll
    for (int fm = 0; fm < 4; ++fm) {
      int row = m0 + wm * 64 + fm * 16 + lg * 4;
      bf16_t* op = O + (size_t)row * 1024 + col;
#pragma unroll
      for (int r = 0; r < 4; ++r)
        op[(size_t)r * 1024] = (bf16_t)((acc[fm][fn][r] + bb2) * scale);
    }
  }
}

// ---------------- proj: 256 blocks; fp32 + bias + residual ----------------
__global__ __launch_bounds__(512, 4) void gemm_proj2(
    const bf16_t* __restrict__ A, const bf16_t* __restrict__ W,
    const float* __restrict__ bias, const float* __restrict__ xres,
    float* __restrict__ Out) {
  __shared__ bf16_t Sm[24576];

  int wg = blockIdx.x;
  int xcd = wg & 7, local = wg >> 3;          // 0..31
  int bm = xcd * 8 + (local & 7);             // 0..63
  int bn = local >> 3;                        // 0..3
  const int m0 = bm * 128, n0 = bn * 256;

  f32x4 acc[4][4] = {};
  core_bk32(A, W, m0, n0, Sm, acc);

  const int tid = threadIdx.x;
  const int l = tid & 63, w = tid >> 6;
  const int wm = w >> 2, wn = w & 3;
  const int lr = l & 15, lg = l >> 4;
#pragma unroll
  for (int fn = 0; fn < 4; ++fn) {
    int col = n0 + wn * 64 + fn * 16 + lr;
    float bb2 = bias[col];
#pragma unroll
    for (int fm = 0; fm < 4; ++fm) {
      int row = m0 + wm * 64 + fm * 16 + lg * 4;
#pragma unroll
      for (int r = 0; r < 4; ++r) {
        size_t idx = (size_t)(row + r) * 1024 + col;
        Out[idx] = acc[fm][fn][r] + bb2 + xres[idx];
      }
    }
  }
}

// ---------------- V transpose via LDS tile (raw-reshape semantics) ----------------
__global__ __launch_bounds__(256) void transpose_v(const bf16_t* __restrict__ V,
                                                   bf16_t* __restrict__ Vt) {
  __shared__ float sT[128 * 33];
  int bh = blockIdx.x >> 3, st = blockIdx.x & 7;
  int s0 = st * 128;
  int t = threadIdx.x;
  const bf16_t* src = V + (size_t)bh * 65536 + (size_t)s0 * 64;
  int li = t >> 3, lc = t & 7;
#pragma unroll
  for (int p = 0; p < 4; ++p) {
    int row = p * 32 + li;
    f32x4 v = *(const f32x4*)(src + (size_t)row * 64 + lc * 8);
    float* dst = &sT[row * 33 + lc * 4];
    dst[0] = v[0]; dst[1] = v[1]; dst[2] = v[2]; dst[3] = v[3];
  }
  __syncthreads();
  int sc = t & 15, dh0 = t >> 4;
  bf16_t* dstb = Vt + (size_t)bh * 65536;
#pragma unroll
  for (int p = 0; p < 4; ++p) {
    int dh = dh0 + p * 16;
    bf16x8 o;
#pragma unroll
    for (int j = 0; j < 8; ++j) {
      int s = sc * 8 + j;
      o[j] = ((const bf16_t*)&sT[s * 33 + (dh >> 1)])[dh & 1];
    }
    *(bf16x8*)(dstb + (size_t)dh * 1024 + s0 + sc * 8) = o;
  }
}

// ---------------- fused attention per (bh, 32-row q tile) ----------------
#define SP_STRIDE 1064
__global__ __launch_bounds__(512, 4) void attn_kernel(
    const bf16_t* __restrict__ Q, const bf16_t* __restrict__ K,
    const bf16_t* __restrict__ Vt, float* __restrict__ alpha,
    bf16_t* __restrict__ ctx) {
  __shared__ bf16_t sP[32][SP_STRIDE];
  __shared__ float sRS[8][32];
  __shared__ float sL[32];

  int id = blockIdx.x;
  int g = id >> 3, x = id & 7;
  int qt = g & 31;
  int bh = ((g >> 5) << 3) | x;
  int q0 = qt * 32;

  const bf16_t* Qb = Q + (size_t)bh * 65536;
  const bf16_t* Kb = K + (size_t)bh * 65536;
  const bf16_t* Vb = Vt + (size_t)bh * 65536;
  float* Ab = alpha + (size_t)bh * 1048576 + (size_t)q0 * 1024;

  int t = threadIdx.x, l = t & 63, w = t >> 6;
  int lr = l & 15, lg = l >> 4;

  bf16x8 qa[2][2];
#pragma unroll
  for (int mi = 0; mi < 2; ++mi)
#pragma unroll
    for (int kk = 0; kk < 2; ++kk)
      qa[mi][kk] = *(const bf16x8*)(Qb + (size_t)(q0 + mi * 16 + lr) * 64 + kk * 32 + lg * 8);

  float pa0 = 0.f, pa1 = 0.f;
#pragma unroll
  for (int tt = 0; tt < 8; ++tt) {
    int n0 = w * 128 + tt * 16;
    bf16x8 kb0 = *(const bf16x8*)(Kb + (size_t)(n0 + lr) * 64 + lg * 8);
    bf16x8 kb1 = *(const bf16x8*)(Kb + (size_t)(n0 + lr) * 64 + 32 + lg * 8);
    f32x4 a0 = {0.f, 0.f, 0.f, 0.f};
    f32x4 a1 = {0.f, 0.f, 0.f, 0.f};
    a0 = mfma16(kb0, qa[0][0], a0);
    a0 = mfma16(kb1, qa[0][1], a0);
    a1 = mfma16(kb0, qa[1][0], a1);
    a1 = mfma16(kb1, qa[1][1], a1);
    bf16x4 w0, w1;
#pragma unroll
    for (int r = 0; r < 4; ++r) {
      float e0 = exp2f(a0[r]);
      float e1 = exp2f(a1[r]);
      pa0 += e0; pa1 += e1;
      w0[r] = (bf16_t)e0;
      w1[r] = (bf16_t)e1;
    }
    *(bf16x4*)&sP[lr][n0 + lg * 4] = w0;
    *(bf16x4*)&sP[16 + lr][n0 + lg * 4] = w1;
  }
  pa0 += __shfl_xor(pa0, 16); pa0 += __shfl_xor(pa0, 32);
  pa1 += __shfl_xor(pa1, 16); pa1 += __shfl_xor(pa1, 32);
  if (l < 16) {
    sRS[w][lr] = pa0;
    sRS[w][16 + lr] = pa1;
  }
  __syncthreads();
  if (t < 32) {
    float s = 0.f;
#pragma unroll
    for (int ww = 0; ww < 8; ++ww) s += sRS[ww][t];
    sL[t] = 1.0f / s;
  }
  __syncthreads();

  {
    int wm = w >> 2, wn = w & 3;
    f32x4 acc = {0.f, 0.f, 0.f, 0.f};
    const bf16_t* vp = Vb + (size_t)(wn * 16 + lr) * 1024 + lg * 8;
    const bf16_t* pp = &sP[wm * 16 + lr][lg * 8];
    int arow = t >> 4, acol = (t & 15) * 4;
    float inv = sL[arow];
    const bf16_t* ap = &sP[arow][acol];
    float* aout = Ab + (size_t)arow * 1024 + acol;
#pragma unroll 4
    for (int n0 = 0; n0 < 1024; n0 += 64) {
      bf16x8 ea0 = *(const bf16x8*)(pp + n0);
      bf16x8 vb0 = *(const bf16x8*)(vp + n0);
      acc = mfma16(ea0, vb0, acc);
      bf16x8 ea1 = *(const bf16x8*)(pp + n0 + 32);
      bf16x8 vb1 = *(const bf16x8*)(vp + n0 + 32);
      acc = mfma16(ea1, vb1, acc);
      bf16x4 p = *(const bf16x4*)(ap + n0);
      f32x4 o;
      o[0] = (float)p[0] * inv;
      o[1] = (float)p[1] * inv;
      o[2] = (float)p[2] * inv;
      o[3] = (float)p[3] * inv;
      __builtin_nontemporal_store(o, (f32x4*)(aout + n0));
    }
    bf16_t* cp = ctx + (size_t)bh * 65536 + (size_t)(q0 + wm * 16 + lg * 4) * 64 + wn * 16 + lr;
#pragma unroll
    for (int r = 0; r < 4; ++r)
      cp[(size_t)r * 64] = (bf16_t)(acc[r] * sL[wm * 16 + lg * 4 + r]);
  }
}

// ---------------- LayerNorm in place on d_out rows ----------------
__global__ __launch_bounds__(256) void ln_kernel(float* __restrict__ io,
                                                 const float* __restrict__ gamma,
                                                 const float* __restrict__ beta) {
  int row = blockIdx.x;
  int t = threadIdx.x;
  float* p = io + (size_t)row * 1024;
  f32x4 v = *(const f32x4*)(p + t * 4);
  float s = v[0] + v[1] + v[2] + v[3];
  float s2 = v[0] * v[0] + v[1] * v[1] + v[2] * v[2] + v[3] * v[3];
#pragma unroll
  for (int off = 1; off <= 32; off <<= 1) {
    s += __shfl_xor(s, off);
    s2 += __shfl_xor(s2, off);
  }
  __shared__ float ps[4], ps2[4];
  int w = t >> 6, l = t & 63;
  if (l == 0) { ps[w] = s; ps2[w] = s2; }
  __syncthreads();
  float S = ps[0] + ps[1] + ps[2] + ps[3];
  float S2 = ps2[0] + ps2[1] + ps2[2] + ps2[3];
  float mu = S * (1.f / 1024.f);
  float var = S2 * (1.f / 1024.f) - mu * mu;
  float rs = rsqrtf(var + 1e-5f);
  f32x4 g = *(const f32x4*)(gamma + t * 4);
  f32x4 b = *(const f32x4*)(beta + t * 4);
  f32x4 o;
  o[0] = (v[0] - mu) * rs * g[0] + b[0];
  o[1] = (v[1] - mu) * rs * g[1] + b[1];
  o[2] = (v[2] - mu) * rs * g[2] + b[2];
  o[3] = (v[3] - mu) * rs * g[3] + b[3];
  *(f32x4*)(p + t * 4) = o;
}

extern "C" void kernel_launch(void* const* d_in, const int* in_sizes, int n_in,
                              void* d_out, int out_size, void* d_ws, size_t ws_size,
                              hipStream_t stream) {
  const float* x = (const float*)d_in[0];
  const float* Wq = (const float*)d_in[1];
  const float* bq = (const float*)d_in[2];
  const float* Wk = (const float*)d_in[3];
  const float* bk = (const float*)d_in[4];
  const float* Wv = (const float*)d_in[5];
  const float* bv = (const float*)d_in[6];
  const float* Wo = (const float*)d_in[7];
  const float* bo = (const float*)d_in[8];
  const float* gamma = (const float*)d_in[9];
  const float* beta = (const float*)d_in[10];

  char* ws = (char*)d_ws;
  size_t off = 0;
  bf16_t* xb = (bf16_t*)(ws + off);  off += (size_t)M_ * D_ * 2;
  bf16_t* Wqb = (bf16_t*)(ws + off); off += (size_t)D_ * D_ * 2;
  bf16_t* Wkb = (bf16_t*)(ws + off); off += (size_t)D_ * D_ * 2;
  bf16_t* Wvb = (bf16_t*)(ws + off); off += (size_t)D_ * D_ * 2;
  bf16_t* Wob = (bf16_t*)(ws + off); off += (size_t)D_ * D_ * 2;
  bf16_t* Qb = (bf16_t*)(ws + off);  off += (size_t)M_ * D_ * 2;
  bf16_t* Kb = (bf16_t*)(ws + off);  off += (size_t)M_ * D_ * 2;
  bf16_t* Vb = (bf16_t*)(ws + off);  off += (size_t)M_ * D_ * 2;
  bf16_t* Vtb = (bf16_t*)(ws + off); off += (size_t)M_ * D_ * 2;
  bf16_t* ctxb = (bf16_t*)(ws + off); off += (size_t)M_ * D_ * 2;

  float* out0 = (float*)d_out;
  float* alpha = out0 + (size_t)M_ * D_;

  cvt_all<<<6144, 256, 0, stream>>>(x, Wq, Wk, Wv, Wo, xb, Wqb, Wkb, Wvb, Wob);

  gemm_qkv2<<<768, 512, 0, stream>>>(xb, Wqb, Wkb, Wvb, bq, bk, bv, Qb, Kb, Vb);
  transpose_v<<<1024, 256, 0, stream>>>(Vb, Vtb);
  attn_kernel<<<4096, 512, 0, stream>>>(Qb, Kb, Vtb, alpha, ctxb);
  gemm_proj2<<<256, 512, 0, stream>>>(ctxb, Wob, bo, x, out0);
  ln_kernel<<<8192, 256, 0, stream>>>(out0, gamma, beta);
}

// Round 16
// 316.969 us; speedup vs baseline: 1.0249x; 1.0249x over previous
//
#include <hip/hip_runtime.h>
#include <stdint.h>
#include <math.h>

typedef __bf16 bf16_t;
typedef float f32x4 __attribute__((ext_vector_type(4)));
typedef __bf16 bf16x8 __attribute__((ext_vector_type(8)));
typedef __bf16 bf16x4 __attribute__((ext_vector_type(4)));

#define D_ 1024
#define M_ 8192

__device__ __forceinline__ f32x4 mfma16(bf16x8 a, bf16x8 b, f32x4 c) {
  return __builtin_amdgcn_mfma_f32_16x16x32_bf16(a, b, c, 0, 0, 0);
}

__device__ __forceinline__ void gl_lds16(const bf16_t* g, bf16_t* l) {
  __builtin_amdgcn_global_load_lds(
      (const __attribute__((address_space(1))) unsigned int*)g,
      (__attribute__((address_space(3))) unsigned int*)l, 16, 0, 0);
}

// ---------------- all fp32 -> bf16 converts in ONE launch ----------------
__global__ __launch_bounds__(256) void cvt_all(
    const float* __restrict__ x,
    const float* __restrict__ w0, const float* __restrict__ w1,
    const float* __restrict__ w2, const float* __restrict__ w3,
    bf16_t* __restrict__ xb,
    bf16_t* __restrict__ d0, bf16_t* __restrict__ d1,
    bf16_t* __restrict__ d2, bf16_t* __restrict__ d3) {
  int b = blockIdx.x;
  const float* s;
  bf16_t* d;
  int i;
  if (b < 4096) {
    s = x; d = xb; i = b * 256 + threadIdx.x;
  } else {
    int g = b - 4096;
    int which = g >> 9;
    s = which == 0 ? w0 : which == 1 ? w1 : which == 2 ? w2 : w3;
    d = which == 0 ? d0 : which == 1 ? d1 : which == 2 ? d2 : d3;
    i = (g & 511) * 256 + threadIdx.x;
  }
  const f32x4* p = (const f32x4*)(s + (size_t)i * 8);
  f32x4 a = p[0], bb = p[1];
  bf16x8 o;
  o[0] = (bf16_t)a.x; o[1] = (bf16_t)a.y; o[2] = (bf16_t)a.z; o[3] = (bf16_t)a.w;
  o[4] = (bf16_t)bb.x; o[5] = (bf16_t)bb.y; o[6] = (bf16_t)bb.z; o[7] = (bf16_t)bb.w;
  *(bf16x8*)(d + (size_t)i * 8) = o;
}

#define LDSB(e) (*(const bf16x8*)(Sm + (e)))

// ================= QKV: 128x384xBK64, fused N=3072 over contiguous W ========
// Wq|Wk|Wv contiguous in ws (Wall); Q|K|V contiguous (Obase). 48 MFMA per
// wave per K-tile. 512 blocks = 2.0 dispatch waves. LDS 128 KiB.
#define STG38(b, kt)                                                          \
  {                                                                           \
    _Pragma("unroll") for (int c = 0; c < 2; ++c)                             \
        gl_lds16(Ap + (size_t)(m0 + c * 64 + srow) * 1024 + (kt) * 64 + scol, \
                 Sm + (b) * 32768 + c * 4096 + tid * 8);                      \
    _Pragma("unroll") for (int c = 0; c < 6; ++c)                             \
        gl_lds16(Wall + (size_t)(n0 + c * 64 + srow) * 1024 + (kt) * 64 + scol,\
                 Sm + (b) * 32768 + 8192 + c * 4096 + tid * 8);               \
  }

__global__ __launch_bounds__(512) void gemm_qkv3(
    const bf16_t* __restrict__ Ap, const bf16_t* __restrict__ Wall,
    const float* __restrict__ bq, const float* __restrict__ bk,
    const float* __restrict__ bv, bf16_t* __restrict__ Obase) {
  __shared__ bf16_t Sm[65536];  // 128 KiB (2 bufs x (A 8K + B 24K elems))

  const int tid = threadIdx.x;
  const int l = tid & 63, w = tid >> 6;
  const int wm = w >> 2, wn = w & 3;
  const int lr = l & 15, lg = l >> 4;

  // XCD chunk: each XCD owns 8 contiguous bm x all 8 bn panels.
  int wg = blockIdx.x;
  int xcd = wg & 7, local = wg >> 3;          // local 0..63
  int bm = xcd * 8 + (local & 7);             // 0..63
  int bn = local >> 3;                        // 0..7
  const int m0 = bm * 128, n0 = bn * 384;

  const int scol = ((l & 7) ^ ((l >> 3) & 7)) * 8;
  const int srow = tid >> 3;  // 0..63
  const int rdA = (wm * 64 + lr) * 64 + (lg ^ (lr & 7)) * 8;
  const int rdB = 8192 + (wn * 96 + lr) * 64 + (lg ^ (lr & 7)) * 8;

  f32x4 acc[4][6] = {};

  STG38(0, 0)
  asm volatile("s_waitcnt vmcnt(0)" ::: "memory");
  __builtin_amdgcn_sched_barrier(0);
  __builtin_amdgcn_s_barrier();

  int cur = 0;
  for (int kt = 0; kt < 16; ++kt) {
    if (kt < 15) STG38(cur ^ 1, kt + 1)
    const int bb = cur * 32768;
    bf16x8 bfr[6][2];
#pragma unroll
    for (int fn = 0; fn < 6; ++fn) {
      bfr[fn][0] = LDSB(bb + rdB + fn * 1024);
      bfr[fn][1] = LDSB((bb + rdB + fn * 1024) ^ 32);
    }
#pragma unroll
    for (int fm = 0; fm < 4; ++fm) {
      bf16x8 a0 = LDSB(bb + rdA + fm * 1024);
      bf16x8 a1 = LDSB((bb + rdA + fm * 1024) ^ 32);
#pragma unroll
      for (int fn = 0; fn < 6; ++fn) {
        acc[fm][fn] = mfma16(a0, bfr[fn][0], acc[fm][fn]);
        acc[fm][fn] = mfma16(a1, bfr[fn][1], acc[fm][fn]);
      }
    }
    asm volatile("s_waitcnt vmcnt(0)" ::: "memory");
    __builtin_amdgcn_sched_barrier(0);
    __builtin_amdgcn_s_barrier();
    cur ^= 1;
  }

  // epilogue: per-fragment matrix select (fragments never cross col 1024k)
#pragma unroll
  for (int fn = 0; fn < 6; ++fn) {
    int col = n0 + wn * 96 + fn * 16 + lr;
    int which = col >> 10, ocol = col & 1023;
    float bb2 = which == 0 ? bq[ocol] : (which == 1 ? bk[ocol] : bv[ocol]);
    float scale = which == 0 ? 0.18033688f : 1.0f;  // 0.125*log2(e) on Q
    bf16_t* ob = Obase + (size_t)which * M_ * D_ + ocol;
#pragma unroll
    for (int fm = 0; fm < 4; ++fm) {
      int row = m0 + wm * 64 + fm * 16 + lg * 4;
      bf16_t* op = ob + (size_t)row * 1024;
#pragma unroll
      for (int r = 0; r < 4; ++r)
        op[(size_t)r * 1024] = (bf16_t)((acc[fm][fn][r] + bb2) * scale);
    }
  }
}

// ============ 2-phase 128x256xBK64 core (proj) — R10-proven =============
#define STG26(b, kt)                                                          \
  {                                                                           \
    _Pragma("unroll") for (int c = 0; c < 2; ++c)                             \
        gl_lds16(Ap + (size_t)(m0 + c * 64 + srow) * 1024 + (kt) * 64 + scol, \
                 Sm + (b) * 24576 + c * 4096 + tid * 8);                      \
    _Pragma("unroll") for (int c = 0; c < 4; ++c)                             \
        gl_lds16(Bp + (size_t)(n0 + c * 64 + srow) * 1024 + (kt) * 64 + scol, \
                 Sm + (b) * 24576 + 8192 + c * 4096 + tid * 8);               \
  }

__device__ __forceinline__ void core_128x256(const bf16_t* __restrict__ Ap,
                                             const bf16_t* __restrict__ Bp,
                                             int m0, int n0, bf16_t* Sm,
                                             f32x4 acc[4][4]) {
  const int tid = threadIdx.x;
  const int l = tid & 63, w = tid >> 6;
  const int wm = w >> 2, wn = w & 3;
  const int lr = l & 15, lg = l >> 4;
  const int scol = ((l & 7) ^ ((l >> 3) & 7)) * 8;
  const int srow = tid >> 3;  // 0..63
  const int rdA = (wm * 64 + lr) * 64 + (lg ^ (lr & 7)) * 8;
  const int rdB = 8192 + (wn * 64 + lr) * 64 + (lg ^ (lr & 7)) * 8;

  STG26(0, 0)
  asm volatile("s_waitcnt vmcnt(0)" ::: "memory");
  __builtin_amdgcn_sched_barrier(0);
  __builtin_amdgcn_s_barrier();

  int cur = 0;
  for (int kt = 0; kt < 16; ++kt) {
    if (kt < 15) STG26(cur ^ 1, kt + 1)
    const int bb = cur * 24576;
    bf16x8 bfr[4][2];
#pragma unroll
    for (int fn = 0; fn < 4; ++fn) {
      bfr[fn][0] = LDSB(bb + rdB + fn * 1024);
      bfr[fn][1] = LDSB((bb + rdB + fn * 1024) ^ 32);
    }
#pragma unroll
    for (int fm = 0; fm < 4; ++fm) {
      bf16x8 a0 = LDSB(bb + rdA + fm * 1024);
      bf16x8 a1 = LDSB((bb + rdA + fm * 1024) ^ 32);
#pragma unroll
      for (int fn = 0; fn < 4; ++fn) {
        acc[fm][fn] = mfma16(a0, bfr[fn][0], acc[fm][fn]);
        acc[fm][fn] = mfma16(a1, bfr[fn][1], acc[fm][fn]);
      }
    }
    asm volatile("s_waitcnt vmcnt(0)" ::: "memory");
    __builtin_amdgcn_sched_barrier(0);
    __builtin_amdgcn_s_barrier();
    cur ^= 1;
  }
}

// ---------------- proj: 256 blocks = 1.0 wave; fp32 + bias + residual ----------------
__global__ __launch_bounds__(512) void gemm_proj2(
    const bf16_t* __restrict__ A, const bf16_t* __restrict__ W,
    const float* __restrict__ bias, const float* __restrict__ xres,
    float* __restrict__ Out) {
  __shared__ bf16_t Sm[49152];

  int wg = blockIdx.x;
  int xcd = wg & 7, local = wg >> 3;          // 0..31
  int bm = xcd * 8 + (local & 7);             // 0..63
  int bn = local >> 3;                        // 0..3
  const int m0 = bm * 128, n0 = bn * 256;

  f32x4 acc[4][4] = {};
  core_128x256(A, W, m0, n0, Sm, acc);

  const int tid = threadIdx.x;
  const int l = tid & 63, w = tid >> 6;
  const int wm = w >> 2, wn = w & 3;
  const int lr = l & 15, lg = l >> 4;
#pragma unroll
  for (int fn = 0; fn < 4; ++fn) {
    int col = n0 + wn * 64 + fn * 16 + lr;
    float bb2 = bias[col];
#pragma unroll
    for (int fm = 0; fm < 4; ++fm) {
      int row = m0 + wm * 64 + fm * 16 + lg * 4;
#pragma unroll
      for (int r = 0; r < 4; ++r) {
        size_t idx = (size_t)(row + r) * 1024 + col;
        Out[idx] = acc[fm][fn][r] + bb2 + xres[idx];
      }
    }
  }
}

// ---------------- V transpose via LDS tile (raw-reshape semantics) ----------------
__global__ __launch_bounds__(256) void transpose_v(const bf16_t* __restrict__ V,
                                                   bf16_t* __restrict__ Vt) {
  __shared__ float sT[128 * 33];
  int bh = blockIdx.x >> 3, st = blockIdx.x & 7;
  int s0 = st * 128;
  int t = threadIdx.x;
  const bf16_t* src = V + (size_t)bh * 65536 + (size_t)s0 * 64;
  int li = t >> 3, lc = t & 7;
#pragma unroll
  for (int p = 0; p < 4; ++p) {
    int row = p * 32 + li;
    f32x4 v = *(const f32x4*)(src + (size_t)row * 64 + lc * 8);
    float* dst = &sT[row * 33 + lc * 4];
    dst[0] = v[0]; dst[1] = v[1]; dst[2] = v[2]; dst[3] = v[3];
  }
  __syncthreads();
  int sc = t & 15, dh0 = t >> 4;
  bf16_t* dstb = Vt + (size_t)bh * 65536;
#pragma unroll
  for (int p = 0; p < 4; ++p) {
    int dh = dh0 + p * 16;
    bf16x8 o;
#pragma unroll
    for (int j = 0; j < 8; ++j) {
      int s = sc * 8 + j;
      o[j] = ((const bf16_t*)&sT[s * 33 + (dh >> 1)])[dh & 1];
    }
    *(bf16x8*)(dstb + (size_t)dh * 1024 + s0 + sc * 8) = o;
  }
}

// ---------------- fused attention per (bh, 32-row q tile) ----------------
#define SP_STRIDE 1064
__global__ __launch_bounds__(512, 4) void attn_kernel(
    const bf16_t* __restrict__ Q, const bf16_t* __restrict__ K,
    const bf16_t* __restrict__ Vt, float* __restrict__ alpha,
    bf16_t* __restrict__ ctx) {
  __shared__ bf16_t sP[32][SP_STRIDE];
  __shared__ float sRS[8][32];
  __shared__ float sL[32];

  int id = blockIdx.x;
  int g = id >> 3, x = id & 7;
  int qt = g & 31;
  int bh = ((g >> 5) << 3) | x;
  int q0 = qt * 32;

  const bf16_t* Qb = Q + (size_t)bh * 65536;
  const bf16_t* Kb = K + (size_t)bh * 65536;
  const bf16_t* Vb = Vt + (size_t)bh * 65536;
  float* Ab = alpha + (size_t)bh * 1048576 + (size_t)q0 * 1024;

  int t = threadIdx.x, l = t & 63, w = t >> 6;
  int lr = l & 15, lg = l >> 4;

  bf16x8 qa[2][2];
#pragma unroll
  for (int mi = 0; mi < 2; ++mi)
#pragma unroll
    for (int kk = 0; kk < 2; ++kk)
      qa[mi][kk] = *(const bf16x8*)(Qb + (size_t)(q0 + mi * 16 + lr) * 64 + kk * 32 + lg * 8);

  float pa0 = 0.f, pa1 = 0.f;
#pragma unroll
  for (int tt = 0; tt < 8; ++tt) {
    int n0 = w * 128 + tt * 16;
    bf16x8 kb0 = *(const bf16x8*)(Kb + (size_t)(n0 + lr) * 64 + lg * 8);
    bf16x8 kb1 = *(const bf16x8*)(Kb + (size_t)(n0 + lr) * 64 + 32 + lg * 8);
    f32x4 a0 = {0.f, 0.f, 0.f, 0.f};
    f32x4 a1 = {0.f, 0.f, 0.f, 0.f};
    a0 = mfma16(kb0, qa[0][0], a0);
    a0 = mfma16(kb1, qa[0][1], a0);
    a1 = mfma16(kb0, qa[1][0], a1);
    a1 = mfma16(kb1, qa[1][1], a1);
    bf16x4 w0, w1;
#pragma unroll
    for (int r = 0; r < 4; ++r) {
      float e0 = exp2f(a0[r]);
      float e1 = exp2f(a1[r]);
      pa0 += e0; pa1 += e1;
      w0[r] = (bf16_t)e0;
      w1[r] = (bf16_t)e1;
    }
    *(bf16x4*)&sP[lr][n0 + lg * 4] = w0;
    *(bf16x4*)&sP[16 + lr][n0 + lg * 4] = w1;
  }
  pa0 += __shfl_xor(pa0, 16); pa0 += __shfl_xor(pa0, 32);
  pa1 += __shfl_xor(pa1, 16); pa1 += __shfl_xor(pa1, 32);
  if (l < 16) {
    sRS[w][lr] = pa0;
    sRS[w][16 + lr] = pa1;
  }
  __syncthreads();
  if (t < 32) {
    float s = 0.f;
#pragma unroll
    for (int ww = 0; ww < 8; ++ww) s += sRS[ww][t];
    sL[t] = 1.0f / s;
  }
  __syncthreads();

  {
    int wm = w >> 2, wn = w & 3;
    f32x4 acc = {0.f, 0.f, 0.f, 0.f};
    const bf16_t* vp = Vb + (size_t)(wn * 16 + lr) * 1024 + lg * 8;
    const bf16_t* pp = &sP[wm * 16 + lr][lg * 8];
    int arow = t >> 4, acol = (t & 15) * 4;
    float inv = sL[arow];
    const bf16_t* ap = &sP[arow][acol];
    float* aout = Ab + (size_t)arow * 1024 + acol;
#pragma unroll 4
    for (int n0 = 0; n0 < 1024; n0 += 64) {
      bf16x8 ea0 = *(const bf16x8*)(pp + n0);
      bf16x8 vb0 = *(const bf16x8*)(vp + n0);
      acc = mfma16(ea0, vb0, acc);
      bf16x8 ea1 = *(const bf16x8*)(pp + n0 + 32);
      bf16x8 vb1 = *(const bf16x8*)(vp + n0 + 32);
      acc = mfma16(ea1, vb1, acc);
      bf16x4 p = *(const bf16x4*)(ap + n0);
      f32x4 o;
      o[0] = (float)p[0] * inv;
      o[1] = (float)p[1] * inv;
      o[2] = (float)p[2] * inv;
      o[3] = (float)p[3] * inv;
      __builtin_nontemporal_store(o, (f32x4*)(aout + n0));
    }
    bf16_t* cp = ctx + (size_t)bh * 65536 + (size_t)(q0 + wm * 16 + lg * 4) * 64 + wn * 16 + lr;
#pragma unroll
    for (int r = 0; r < 4; ++r)
      cp[(size_t)r * 64] = (bf16_t)(acc[r] * sL[wm * 16 + lg * 4 + r]);
  }
}

// ---------------- LayerNorm in place on d_out rows ----------------
__global__ __launch_bounds__(256) void ln_kernel(float* __restrict__ io,
                                                 const float* __restrict__ gamma,
                                                 const float* __restrict__ beta) {
  int row = blockIdx.x;
  int t = threadIdx.x;
  float* p = io + (size_t)row * 1024;
  f32x4 v = *(const f32x4*)(p + t * 4);
  float s = v[0] + v[1] + v[2] + v[3];
  float s2 = v[0] * v[0] + v[1] * v[1] + v[2] * v[2] + v[3] * v[3];
#pragma unroll
  for (int off = 1; off <= 32; off <<= 1) {
    s += __shfl_xor(s, off);
    s2 += __shfl_xor(s2, off);
  }
  __shared__ float ps[4], ps2[4];
  int w = t >> 6, l = t & 63;
  if (l == 0) { ps[w] = s; ps2[w] = s2; }
  __syncthreads();
  float S = ps[0] + ps[1] + ps[2] + ps[3];
  float S2 = ps2[0] + ps2[1] + ps2[2] + ps2[3];
  float mu = S * (1.f / 1024.f);
  float var = S2 * (1.f / 1024.f) - mu * mu;
  float rs = rsqrtf(var + 1e-5f);
  f32x4 g = *(const f32x4*)(gamma + t * 4);
  f32x4 b = *(const f32x4*)(beta + t * 4);
  f32x4 o;
  o[0] = (v[0] - mu) * rs * g[0] + b[0];
  o[1] = (v[1] - mu) * rs * g[1] + b[1];
  o[2] = (v[2] - mu) * rs * g[2] + b[2];
  o[3] = (v[3] - mu) * rs * g[3] + b[3];
  *(f32x4*)(p + t * 4) = o;
}

extern "C" void kernel_launch(void* const* d_in, const int* in_sizes, int n_in,
                              void* d_out, int out_size, void* d_ws, size_t ws_size,
                              hipStream_t stream) {
  const float* x = (const float*)d_in[0];
  const float* Wq = (const float*)d_in[1];
  const float* bq = (const float*)d_in[2];
  const float* Wk = (const float*)d_in[3];
  const float* bk = (const float*)d_in[4];
  const float* Wv = (const float*)d_in[5];
  const float* bv = (const float*)d_in[6];
  const float* Wo = (const float*)d_in[7];
  const float* bo = (const float*)d_in[8];
  const float* gamma = (const float*)d_in[9];
  const float* beta = (const float*)d_in[10];

  char* ws = (char*)d_ws;
  size_t off = 0;
  bf16_t* xb = (bf16_t*)(ws + off);  off += (size_t)M_ * D_ * 2;
  // Wqb|Wkb|Wvb contiguous => fused W matrix [3072][1024]
  bf16_t* Wqb = (bf16_t*)(ws + off); off += (size_t)D_ * D_ * 2;
  bf16_t* Wkb = (bf16_t*)(ws + off); off += (size_t)D_ * D_ * 2;
  bf16_t* Wvb = (bf16_t*)(ws + off); off += (size_t)D_ * D_ * 2;
  bf16_t* Wob = (bf16_t*)(ws + off); off += (size_t)D_ * D_ * 2;
  // Qb|Kb|Vb contiguous => fused output [3][8192][1024]
  bf16_t* Qb = (bf16_t*)(ws + off);  off += (size_t)M_ * D_ * 2;
  bf16_t* Kb = (bf16_t*)(ws + off);  off += (size_t)M_ * D_ * 2;
  bf16_t* Vb = (bf16_t*)(ws + off);  off += (size_t)M_ * D_ * 2;
  bf16_t* Vtb = (bf16_t*)(ws + off); off += (size_t)M_ * D_ * 2;
  bf16_t* ctxb = (bf16_t*)(ws + off); off += (size_t)M_ * D_ * 2;

  float* out0 = (float*)d_out;
  float* alpha = out0 + (size_t)M_ * D_;

  cvt_all<<<6144, 256, 0, stream>>>(x, Wq, Wk, Wv, Wo, xb, Wqb, Wkb, Wvb, Wob);

  gemm_qkv3<<<512, 512, 0, stream>>>(xb, Wqb, bq, bk, bv, Qb);
  transpose_v<<<1024, 256, 0, stream>>>(Vb, Vtb);
  attn_kernel<<<4096, 512, 0, stream>>>(Qb, Kb, Vtb, alpha, ctxb);
  gemm_proj2<<<256, 512, 0, stream>>>(ctxb, Wob, bo, x, out0);
  ln_kernel<<<8192, 256, 0, stream>>>(out0, gamma, beta);
}